// Round 11
// baseline (4139.680 us; speedup 1.0000x reference)
//
#include <hip/hip_runtime.h>
#include <hip/hip_bf16.h>
#include <math.h>

#define Bz 64
#define Sz 256
#define Dz 256
#define Hz 512
#define FH 2048   // 4H
#define OH 1024   // 2H
#define Tz 48
#define EPSV 1e-5f
#define LOG2E 1.44269504f

typedef __hip_bfloat16 bf16;
typedef __attribute__((ext_vector_type(8))) short short8;
typedef __attribute__((ext_vector_type(4))) float floatx4;
typedef unsigned long long u64;

__device__ __forceinline__ float b2f(bf16 v){ return __bfloat162float(v); }
// fast sigmoid/tanh on v_exp_f32 / v_rcp_f32
__device__ __forceinline__ float fsig(float x){
  float e = __builtin_amdgcn_exp2f(-x*LOG2E);
  return __builtin_amdgcn_rcpf(1.f + e);
}
__device__ __forceinline__ float ftanh(float x){
  float e = __builtin_amdgcn_exp2f(x*(2.f*LOG2E));
  return 1.f - 2.f*__builtin_amdgcn_rcpf(e + 1.f);
}

__device__ __forceinline__ void load4f(const bf16* p, float v[4]) {
  ushort4 t = *(const ushort4*)p;
  v[0] = __uint_as_float(((unsigned)t.x) << 16);
  v[1] = __uint_as_float(((unsigned)t.y) << 16);
  v[2] = __uint_as_float(((unsigned)t.z) << 16);
  v[3] = __uint_as_float(((unsigned)t.w) << 16);
}
__device__ __forceinline__ void storev(float* p, float v){ *p = v; }
__device__ __forceinline__ void storev(bf16* p, float v){ *p = __float2bfloat16(v); }

// ---------- fp32 -> bf16 cast ----------
__global__ __launch_bounds__(256) void castf2b(const float* __restrict__ in, bf16* __restrict__ out, int n)
{
  int i = (blockIdx.x*256 + threadIdx.x)*4;
  if (i >= n) return;
  float4 v = *(const float4*)(in + i);
  bf16 tmp[4];
  tmp[0] = __float2bfloat16(v.x); tmp[1] = __float2bfloat16(v.y);
  tmp[2] = __float2bfloat16(v.z); tmp[3] = __float2bfloat16(v.w);
  *(uint2*)(out + i) = *(const uint2*)tmp;
}

__global__ __launch_bounds__(256) void bnprep_k(const float* __restrict__ gamma, const float* __restrict__ beta,
  const float* __restrict__ mean, const float* __restrict__ var,
  float* __restrict__ scale, float* __restrict__ shift)
{
  int i = blockIdx.x*256 + threadIdx.x;
  if (i >= OH) return;
  float s = gamma[i]*rsqrtf(var[i]+EPSV);
  scale[i] = s; shift[i] = beta[i] - mean[i]*s;
}

// ---------- MFMA bf16 GEMM: C = A(MxK) * W(NxK)^T + b1 + b2, opt relu ----------
template<typename TC>
__global__ __launch_bounds__(256) void gemm_mfma(
  const bf16* __restrict__ A, const bf16* __restrict__ W,
  const float* __restrict__ b1, const float* __restrict__ b2,
  TC* __restrict__ Cv, int M, int N, int K, int relu)
{
  __shared__ bf16 As[128][40];
  __shared__ bf16 Bs[128][40];
  int tid = threadIdx.x;
  int wave = tid>>6, lane = tid&63, l15 = lane&15, quad = lane>>4;
  int m0 = blockIdx.y*128, n0 = blockIdx.x*128;
  int wm = (wave>>1)*64, wn = (wave&1)*64;
  int srow = tid>>1, scw = (tid&1)*16;
  const bf16* Ap = A + (size_t)(m0+srow)*K + scw;
  const bf16* Wp = W + (size_t)(n0+srow)*K + scw;
  floatx4 zero = {0.f,0.f,0.f,0.f};
  floatx4 acc[4][4];
  #pragma unroll
  for (int i=0;i<4;i++)
    #pragma unroll
    for (int j=0;j<4;j++) acc[i][j] = zero;

  for (int k0 = 0; k0 < K; k0 += 32) {
    float4 a0 = *(const float4*)Ap, a1 = *(const float4*)(Ap+8);
    float4 w0 = *(const float4*)Wp, w1 = *(const float4*)(Wp+8);
    Ap += 32; Wp += 32;
    __syncthreads();
    *(float4*)&As[srow][scw]   = a0; *(float4*)&As[srow][scw+8] = a1;
    *(float4*)&Bs[srow][scw]   = w0; *(float4*)&Bs[srow][scw+8] = w1;
    __syncthreads();
    short8 af[4], bfv[4];
    #pragma unroll
    for (int mi=0;mi<4;mi++) af[mi]  = *(const short8*)&As[wm+mi*16+l15][quad*8];
    #pragma unroll
    for (int ni=0;ni<4;ni++) bfv[ni] = *(const short8*)&Bs[wn+ni*16+l15][quad*8];
    #pragma unroll
    for (int mi=0;mi<4;mi++)
      #pragma unroll
      for (int ni=0;ni<4;ni++)
        acc[mi][ni] = __builtin_amdgcn_mfma_f32_16x16x32_bf16(af[mi], bfv[ni], acc[mi][ni], 0,0,0);
  }
  #pragma unroll
  for (int mi=0;mi<4;mi++){
    #pragma unroll
    for (int ni=0;ni<4;ni++){
      int n = n0 + wn + ni*16 + l15;
      float bb = (b1 ? b1[n] : 0.f) + (b2 ? b2[n] : 0.f);
      #pragma unroll
      for (int r=0;r<4;r++){
        int m = m0 + wm + mi*16 + quad*4 + r;
        float v = acc[mi][ni][r] + bb;
        if (relu) v = fmaxf(v, 0.f);
        storev(&Cv[(size_t)m*N + n], v);
      }
    }
  }
}

// ---------- naive GEMM for fc3 (N=48) ----------
__global__ __launch_bounds__(256) void gemm_nt_small(
  const bf16* __restrict__ A, const float* __restrict__ W,
  const float* __restrict__ b1, float* __restrict__ Cv, int M, int N, int K)
{
  __shared__ float As[8][128];
  __shared__ float Ws[8][128];
  int tid = threadIdx.x;
  int tx = tid & 15, ty = tid >> 4;
  int m0 = blockIdx.y * 128, n0 = blockIdx.x * 128;
  int sr = tid >> 1;
  int sk = (tid & 1) * 4;
  const bf16* Ap = A + (size_t)(m0 + sr) * K + sk;
  bool wok = (n0 + sr) < N;
  const float* Wp = W + (size_t)(wok ? (n0 + sr) : 0) * K + sk;
  float acc[8][8] = {};
  for (int k0 = 0; k0 < K; k0 += 8) {
    float av[4], wv[4];
    load4f(Ap, av);
    if (wok) { float4 t = *(const float4*)Wp; wv[0]=t.x; wv[1]=t.y; wv[2]=t.z; wv[3]=t.w; }
    else { wv[0]=wv[1]=wv[2]=wv[3]=0.f; }
    Ap += 8; Wp += 8;
    __syncthreads();
    As[sk+0][sr]=av[0]; As[sk+1][sr]=av[1]; As[sk+2][sr]=av[2]; As[sk+3][sr]=av[3];
    Ws[sk+0][sr]=wv[0]; Ws[sk+1][sr]=wv[1]; Ws[sk+2][sr]=wv[2]; Ws[sk+3][sr]=wv[3];
    __syncthreads();
    #pragma unroll
    for (int kk = 0; kk < 8; kk++) {
      float a[8], w[8];
      *(float4*)&a[0] = *(const float4*)&As[kk][ty*8];
      *(float4*)&a[4] = *(const float4*)&As[kk][ty*8+4];
      *(float4*)&w[0] = *(const float4*)&Ws[kk][tx*8];
      *(float4*)&w[4] = *(const float4*)&Ws[kk][tx*8+4];
      #pragma unroll
      for (int i=0;i<8;i++)
        #pragma unroll
        for (int j=0;j<8;j++) acc[i][j] += a[i]*w[j];
    }
  }
  #pragma unroll
  for (int i=0;i<8;i++){
    int m = m0 + ty*8 + i;
    #pragma unroll
    for (int j=0;j<8;j++){
      int n = n0 + tx*8 + j;
      if (n < N) Cv[(size_t)m*N + n] = acc[i][j] + b1[n];
    }
  }
}

// ---------- persistent BiLSTM layer: 64 blocks = dir(2) x jslice(32 of 16 units) ----------
// v11 = v10b + L2-SHARED h loads. The 8 blocks on each XCD all read the same 128KB
// of h every step; system-scope loads fetched each line 8x from the MALL. Changes:
//  * af loads become NORMAL cached b128 loads (same block-major addresses): L2
//    MSHRs merge the 8 same-XCD blocks' concurrent misses -> one MALL fetch per
//    line per XCD, 7/8 of load traffic becomes ~150cy L2 hits.
//  * release fence becomes a real agent-scope ACQUIRE fence (one buffer_inv per
//    step) so stale L2 copies are dropped before the next step's loads (v2-proven
//    correct; producers' system-scope write-through keeps the MALL fresh).
// Everything else byte-identical to v10b: block-major h, LDS-staged wide stores
// (128 threads x 2x8B line-contiguous), af-first/pgn-behind schedule,
// __syncthreads + tid0 fetch_add arrival, autonomous counter poll, xout after stamp.
__global__ __launch_bounds__(256,1) void lstm_persist(
  const bf16* __restrict__ preF, const bf16* __restrict__ preB,
  const bf16* __restrict__ WF, const bf16* __restrict__ WB,   // Whh bf16 2048x512 row-major
  bf16* __restrict__ hbuf,          // BLOCK-MAJOR [2 pp][2 dir][32][64][16]
  bf16* __restrict__ xout,          // [64][256][1024]
  const float* __restrict__ bnscale, const float* __restrict__ bnshift,
  int* __restrict__ cnt)            // [2 dir][256 steps], zeroed before launch
{
  __shared__ bf16 wlds[64][520];    // 64 gate-rows x 512 k, +8 pad
  __shared__ bf16 htmp[64][16];     // h staging: [b][unit-local]
  int blk = blockIdx.x;
  int dir = blk & 1;
  int js  = blk >> 1;               // 0..31
  int j0  = js * 16;
  const bf16* pre = dir ? preB : preF;
  const bf16* W   = dir ? WB : WF;
  int colOff = dir ? Hz : 0;
  int tid = threadIdx.x;
  int wave = tid >> 6, lane = tid & 63, l15 = lane & 15, quad = lane >> 4;
  int* myc = cnt + dir*256;

  // --- load weight slice once: lds row n = g*16+idx <-> Whh row g*512 + j0 + idx ---
  for (int chunk = tid; chunk < 64*64; chunk += 256) {
    int n = chunk >> 6, col = (chunk & 63) * 8;
    int g = n >> 4, idx = n & 15;
    *(float4*)&wlds[n][col] = *(const float4*)(W + ((size_t)(g*512 + j0 + idx))*Hz + col);
  }
  __syncthreads();

  int bb = wave*16 + quad*4;        // batch base for this lane's accumulator rows
  int j  = j0 + l15;                // this lane's hidden unit
  float sc = bnscale ? bnscale[colOff + j] : 1.f;
  float sh = bnshift ? bnshift[colOff + j] : 0.f;
  int useBN = bnscale ? 1 : 0;
  float c[4] = {0.f,0.f,0.f,0.f};

  // prefetch pre-activations for step 0
  float pg[4][4];
  {
    int t0 = dir ? (Sz-1) : 0;
    #pragma unroll
    for (int r=0;r<4;r++){
      const bf16* pb = pre + ((size_t)(bb+r)*Sz + t0)*FH;
      #pragma unroll
      for (int g=0;g<4;g++) pg[g][r] = b2f(pb[g*512 + j]);
    }
  }

  for (int t = 0; t < Sz; t++) {
    int tcur = dir ? (Sz-1-t) : t;
    floatx4 zero = {0.f,0.f,0.f,0.f};
    floatx4 acc[4] = {zero, zero, zero, zero};

    // 1) h fragments as NORMAL cached b128 loads (L2-shareable across the XCD's
    //    8 blocks; stale copies were invalidated by the acquire fence at the end
    //    of the previous iteration). Block-major: fragment (ks,quad) -> region
    //    js' = 2*ks + (quad>>1), local offset (quad&1)*8.
    short8 af[16];
    if (t > 0) {
      const bf16* hprev = hbuf + ((size_t)((t&1)*2 + dir))*Bz*Hz;
      #pragma unroll
      for (int ks=0;ks<16;ks++){
        int jsrc = 2*ks + (quad>>1);
        af[ks] = *(const short8*)(hprev + ((size_t)(jsrc*64 + wave*16 + l15)*16 + (quad&1)*8));
      }
    }

    // 2) prefetch NEXT step's pre-activations, issued BEHIND the h loads:
    //    MFMA waits only on af (partial vmcnt); these drain under MFMA+gates+barrier
    //    and are consumed next iteration. Normal cached loads.
    float pgn[4][4];
    if (t+1 < Sz) {
      int tnext = dir ? (Sz-2-t) : (t+1);
      #pragma unroll
      for (int r=0;r<4;r++){
        const bf16* pb = pre + ((size_t)(bb+r)*Sz + tnext)*FH;
        #pragma unroll
        for (int g=0;g<4;g++) pgn[g][r] = b2f(pb[g*512 + j]);
      }
    }

    // 3) MFMA (needs only af)
    if (t > 0) {
      #pragma unroll
      for (int g=0; g<4; g++)
        #pragma unroll
        for (int ks=0; ks<16; ks++){
          short8 bfv = *(const short8*)&wlds[g*16 + l15][ks*32 + quad*8];
          acc[g] = __builtin_amdgcn_mfma_f32_16x16x32_bf16(af[ks], bfv, acc[g], 0,0,0);
        }
    }

    // 4) gates (pg prefetched last iteration); h goes to LDS staging buffer
    float hval[4];
    #pragma unroll
    for (int r=0;r<4;r++){
      float gi = acc[0][r] + pg[0][r];
      float gf = acc[1][r] + pg[1][r];
      float gg = acc[2][r] + pg[2][r];
      float go = acc[3][r] + pg[3][r];
      float cv = fsig(gf)*c[r] + fsig(gi)*ftanh(gg);
      float h  = fsig(go)*ftanh(cv);
      c[r] = cv;
      hval[r] = h;
      htmp[bb+r][l15] = __float2bfloat16(h);
    }

    if (t < Sz-1) {
      // 5) coalesced h publish: 128 threads x two contiguous 8B MALL stores
      //    (system-scope write-through keeps the coherence point fresh), then
      //    rendezvous (drains vmcnt) and ONE RMW stamp per block.
      __syncthreads();                       // htmp complete
      if (tid < 128) {
        int b = tid >> 1, half = tid & 1;
        bf16* hnext = hbuf + ((size_t)(((t+1)&1)*2 + dir))*Bz*Hz;
        u64* dst = (u64*)(hnext + ((size_t)(js*64 + b)*16 + half*8));
        const u64* src = (const u64*)&htmp[b][half*8];
        u64 v0 = src[0], v1 = src[1];
        __hip_atomic_store(dst,     v0, __ATOMIC_RELAXED, __HIP_MEMORY_SCOPE_SYSTEM);
        __hip_atomic_store(dst + 1, v1, __ATOMIC_RELAXED, __HIP_MEMORY_SCOPE_SYSTEM);
      }
      asm volatile("s_waitcnt vmcnt(0) lgkmcnt(0)" ::: "memory");
      __syncthreads();                       // all stores drained before stamp
      if (tid == 0)
        __hip_atomic_fetch_add(&myc[t], 1, __ATOMIC_RELAXED, __HIP_MEMORY_SCOPE_SYSTEM);

      // 6) xout stores after the stamp: acks overlap the poll
      #pragma unroll
      for (int r=0;r<4;r++){
        float xv = useBN ? (hval[r]*sc + sh) : hval[r];
        xout[((size_t)(bb+r)*Sz + tcur)*OH + colOff + j] = __float2bfloat16(xv);
      }

      // 7) release: poll the counter, then ONE agent acquire fence (buffer_inv)
      //    so next step's normal h loads can't see stale L2 lines.
      while (__hip_atomic_load(&myc[t], __ATOMIC_RELAXED, __HIP_MEMORY_SCOPE_SYSTEM) < 32) {}
      __builtin_amdgcn_fence(__ATOMIC_ACQUIRE, "agent");

      #pragma unroll
      for (int g=0;g<4;g++)
        #pragma unroll
        for (int r=0;r<4;r++) pg[g][r] = pgn[g][r];
    } else {
      #pragma unroll
      for (int r=0;r<4;r++){
        float xv = useBN ? (hval[r]*sc + sh) : hval[r];
        xout[((size_t)(bb+r)*Sz + tcur)*OH + colOff + j] = __float2bfloat16(xv);
      }
    }
  }
}

// ---------- CRF ----------
__global__ __launch_bounds__(64) void crf_k(const float* __restrict__ em, const int* __restrict__ tags,
  const float* __restrict__ start, const float* __restrict__ endv, const float* __restrict__ trans,
  float* __restrict__ result)
{
  __shared__ float tr[Tz*Tz];
  __shared__ float alpha[2][Tz];
  int b = blockIdx.x, tid = threadIdx.x;
  for (int i = tid; i < Tz*Tz; i += 64) tr[i] = trans[i];
  float np = 0.f;
  for (int t = tid; t < Sz; t += 64) {
    int tg = tags[b*Sz + t];
    np += em[((size_t)b*Sz + t)*Tz + tg];
    if (t+1 < Sz) np += trans[tg*Tz + tags[b*Sz + t + 1]];
  }
  #pragma unroll
  for (int off = 32; off; off >>= 1) np += __shfl_down(np, off);
  float num = 0.f;
  if (tid == 0) num = np + start[tags[b*Sz]] + endv[tags[b*Sz + Sz-1]];
  if (tid < Tz) alpha[0][tid] = start[tid] + em[((size_t)b*Sz)*Tz + tid];
  __syncthreads();
  int cur = 0;
  for (int t = 1; t < Sz; t++) {
    if (tid < Tz) {
      float m = -1e30f;
      for (int i = 0; i < Tz; i++) m = fmaxf(m, alpha[cur][i] + tr[i*Tz + tid]);
      float sum = 0.f;
      for (int i = 0; i < Tz; i++) sum += expf(alpha[cur][i] + tr[i*Tz + tid] - m);
      alpha[1-cur][tid] = m + logf(sum) + em[((size_t)b*Sz + t)*Tz + tid];
    }
    cur ^= 1;
    __syncthreads();
  }
  float a = (tid < Tz) ? alpha[cur][tid] + endv[tid] : -1e30f;
  float m = a;
  #pragma unroll
  for (int off = 32; off; off >>= 1) m = fmaxf(m, __shfl_down(m, off));
  m = __shfl(m, 0);
  float e = (tid < Tz) ? expf(a - m) : 0.f;
  #pragma unroll
  for (int off = 32; off; off >>= 1) e += __shfl_down(e, off);
  if (tid == 0) result[b] = num - (m + logf(e));
}

__global__ __launch_bounds__(64) void finalize_k(const float* __restrict__ result, float* __restrict__ outp)
{
  float v = result[threadIdx.x];
  #pragma unroll
  for (int off = 32; off; off >>= 1) v += __shfl_down(v, off);
  if (threadIdx.x == 0) outp[0] = -(v * (1.f/64.f));
}

extern "C" void kernel_launch(void* const* d_in, const int* in_sizes, int n_in,
                              void* d_out, int out_size, void* d_ws, size_t ws_size,
                              hipStream_t stream)
{
  (void)in_sizes; (void)n_in; (void)out_size; (void)ws_size;
  const float* inputs = (const float*)d_in[0];
  const int*   tags   = (const int*)d_in[1];
  const float* Wih[2][2] = {{(const float*)d_in[2],  (const float*)d_in[6]},
                            {(const float*)d_in[10], (const float*)d_in[14]}};
  const float* Whh[2][2] = {{(const float*)d_in[3],  (const float*)d_in[7]},
                            {(const float*)d_in[11], (const float*)d_in[15]}};
  const float* bih[2][2] = {{(const float*)d_in[4],  (const float*)d_in[8]},
                            {(const float*)d_in[12], (const float*)d_in[16]}};
  const float* bhh[2][2] = {{(const float*)d_in[5],  (const float*)d_in[9]},
                            {(const float*)d_in[13], (const float*)d_in[17]}};
  const float* bn_gamma = (const float*)d_in[18];
  const float* bn_beta  = (const float*)d_in[19];
  const float* bn_mean  = (const float*)d_in[20];
  const float* bn_var   = (const float*)d_in[21];
  const float* fc1_w = (const float*)d_in[22];
  const float* fc1_b = (const float*)d_in[23];
  const float* fc2_w = (const float*)d_in[24];
  const float* fc2_b = (const float*)d_in[25];
  const float* fc3_w = (const float*)d_in[26];
  const float* fc3_b = (const float*)d_in[27];
  const float* crf_start = (const float*)d_in[28];
  const float* crf_end   = (const float*)d_in[29];
  const float* crf_trans = (const float*)d_in[30];

  const size_t M = (size_t)Bz*Sz;   // 16384
  char* p = (char*)d_ws;
  auto alloc = [&](size_t bytes) { char* r = p; p += (bytes + 255) & ~(size_t)255; return r; };
  bf16*  preF  = (bf16*) alloc(M*FH*sizeof(bf16));            // 64 MB
  bf16*  preB  = (bf16*) alloc(M*FH*sizeof(bf16));            // 64 MB
  bf16*  xbuf  = (bf16*) alloc(M*OH*sizeof(bf16));            // 32 MB
  bf16*  inbf  = (bf16*) alloc(M*Dz*sizeof(bf16));            // 8 MB (em overlays later)
  bf16*  Wih0A = (bf16*) alloc((size_t)FH*Dz*sizeof(bf16));   // 1 MB
  bf16*  Wih0B = (bf16*) alloc((size_t)FH*Dz*sizeof(bf16));
  bf16*  Wih1A = (bf16*) alloc((size_t)FH*OH*sizeof(bf16));   // 4 MB
  bf16*  Wih1B = (bf16*) alloc((size_t)FH*OH*sizeof(bf16));
  bf16*  Whh0A = (bf16*) alloc((size_t)FH*Hz*sizeof(bf16));   // 2 MB
  bf16*  Whh0B = (bf16*) alloc((size_t)FH*Hz*sizeof(bf16));
  bf16*  Whh1A = (bf16*) alloc((size_t)FH*Hz*sizeof(bf16));
  bf16*  Whh1B = (bf16*) alloc((size_t)FH*Hz*sizeof(bf16));
  bf16*  fc1wb = (bf16*) alloc((size_t)Hz*OH*sizeof(bf16));   // 1 MB
  bf16*  fc2wb = (bf16*) alloc((size_t)256*Hz*sizeof(bf16));  // 0.25 MB
  bf16*  hbuf  = (bf16*) alloc(4*(size_t)Bz*Hz*sizeof(bf16)); // 256 KB (pp x dir, block-major)
  int*   cnt   = (int*)  alloc(1024*sizeof(int));             // 2 layers x (2 dir x 256 steps)
  float* bnscale = (float*)alloc(OH*sizeof(float));
  float* bnshift = (float*)alloc(OH*sizeof(float));
  float* result  = (float*)alloc(Bz*sizeof(float));
  float* em   = (float*)inbf;                                 // overlay (3 MB <= 8 MB)
  bf16* fc1o = (bf16*)preF;                                   // overlays after recurrence
  bf16* fc2o = (bf16*)preB;

  dim3 tb(256);
  auto cast = [&](const float* src, bf16* dst, size_t n){
    castf2b<<<(n/4 + 255)/256, tb, 0, stream>>>(src, dst, (int)n);
  };

  // barrier counters must be zero (ws is poisoned 0xAA before every run)
  hipMemsetAsync(cnt, 0, 1024*sizeof(int), stream);
  // upfront casts (all independent of compute)
  cast(inputs, inbf, M*Dz);
  cast(Wih[0][0], Wih0A, (size_t)FH*Dz);
  cast(Wih[0][1], Wih0B, (size_t)FH*Dz);
  cast(Wih[1][0], Wih1A, (size_t)FH*OH);
  cast(Wih[1][1], Wih1B, (size_t)FH*OH);
  cast(Whh[0][0], Whh0A, (size_t)FH*Hz);
  cast(Whh[0][1], Whh0B, (size_t)FH*Hz);
  cast(Whh[1][0], Whh1A, (size_t)FH*Hz);
  cast(Whh[1][1], Whh1B, (size_t)FH*Hz);
  cast(fc1_w, fc1wb, (size_t)Hz*OH);
  cast(fc2_w, fc2wb, (size_t)256*Hz);
  bnprep_k<<<OH/256, tb, 0, stream>>>(bn_gamma, bn_beta, bn_mean, bn_var, bnscale, bnshift);

  // ---- layer 0 ----
  gemm_mfma<bf16><<<dim3(FH/128, M/128), tb, 0, stream>>>(inbf, Wih0A, bih[0][0], bhh[0][0], preF, M, FH, Dz, 0);
  gemm_mfma<bf16><<<dim3(FH/128, M/128), tb, 0, stream>>>(inbf, Wih0B, bih[0][1], bhh[0][1], preB, M, FH, Dz, 0);
  lstm_persist<<<64, tb, 0, stream>>>(preF, preB, Whh0A, Whh0B, hbuf, xbuf, nullptr, nullptr, cnt);
  // ---- layer 1 ----
  gemm_mfma<bf16><<<dim3(FH/128, M/128), tb, 0, stream>>>(xbuf, Wih1A, bih[1][0], bhh[1][0], preF, M, FH, OH, 0);
  gemm_mfma<bf16><<<dim3(FH/128, M/128), tb, 0, stream>>>(xbuf, Wih1B, bih[1][1], bhh[1][1], preB, M, FH, OH, 0);
  lstm_persist<<<64, tb, 0, stream>>>(preF, preB, Whh1A, Whh1B, hbuf, xbuf, bnscale, bnshift, cnt + 512);
  // ---- head ----
  gemm_mfma<bf16><<<dim3(Hz/128, M/128), tb, 0, stream>>>(xbuf, fc1wb, fc1_b, nullptr, fc1o, M, Hz, OH, 1);
  gemm_mfma<bf16><<<dim3(256/128, M/128), tb, 0, stream>>>(fc1o, fc2wb, fc2_b, nullptr, fc2o, M, 256, Hz, 1);
  gemm_nt_small<<<dim3(1, M/128), tb, 0, stream>>>(fc2o, fc3_w, fc3_b, em, M, Tz, 256);
  crf_k<<<Bz, 64, 0, stream>>>(em, tags, crf_start, crf_end, crf_trans, result);
  finalize_k<<<1, 64, 0, stream>>>(result, (float*)d_out);
}

// Round 12
// 3706.236 us; speedup vs baseline: 1.1169x; 1.1169x over previous
//
#include <hip/hip_runtime.h>
#include <hip/hip_bf16.h>
#include <math.h>

#define Bz 64
#define Sz 256
#define Dz 256
#define Hz 512
#define FH 2048   // 4H
#define OH 1024   // 2H
#define Tz 48
#define EPSV 1e-5f
#define LOG2E 1.44269504f

typedef __hip_bfloat16 bf16;
typedef __attribute__((ext_vector_type(8))) short short8;
typedef __attribute__((ext_vector_type(4))) float floatx4;
typedef unsigned long long u64;

__device__ __forceinline__ float b2f(bf16 v){ return __bfloat162float(v); }
// fast sigmoid/tanh on v_exp_f32 / v_rcp_f32
__device__ __forceinline__ float fsig(float x){
  float e = __builtin_amdgcn_exp2f(-x*LOG2E);
  return __builtin_amdgcn_rcpf(1.f + e);
}
__device__ __forceinline__ float ftanh(float x){
  float e = __builtin_amdgcn_exp2f(x*(2.f*LOG2E));
  return 1.f - 2.f*__builtin_amdgcn_rcpf(e + 1.f);
}

__device__ __forceinline__ void load4f(const bf16* p, float v[4]) {
  ushort4 t = *(const ushort4*)p;
  v[0] = __uint_as_float(((unsigned)t.x) << 16);
  v[1] = __uint_as_float(((unsigned)t.y) << 16);
  v[2] = __uint_as_float(((unsigned)t.z) << 16);
  v[3] = __uint_as_float(((unsigned)t.w) << 16);
}
__device__ __forceinline__ void storev(float* p, float v){ *p = v; }
__device__ __forceinline__ void storev(bf16* p, float v){ *p = __float2bfloat16(v); }

// ---------- fp32 -> bf16 cast ----------
__global__ __launch_bounds__(256) void castf2b(const float* __restrict__ in, bf16* __restrict__ out, int n)
{
  int i = (blockIdx.x*256 + threadIdx.x)*4;
  if (i >= n) return;
  float4 v = *(const float4*)(in + i);
  bf16 tmp[4];
  tmp[0] = __float2bfloat16(v.x); tmp[1] = __float2bfloat16(v.y);
  tmp[2] = __float2bfloat16(v.z); tmp[3] = __float2bfloat16(v.w);
  *(uint2*)(out + i) = *(const uint2*)tmp;
}

__global__ __launch_bounds__(256) void bnprep_k(const float* __restrict__ gamma, const float* __restrict__ beta,
  const float* __restrict__ mean, const float* __restrict__ var,
  float* __restrict__ scale, float* __restrict__ shift)
{
  int i = blockIdx.x*256 + threadIdx.x;
  if (i >= OH) return;
  float s = gamma[i]*rsqrtf(var[i]+EPSV);
  scale[i] = s; shift[i] = beta[i] - mean[i]*s;
}

// ---------- MFMA bf16 GEMM: C = A(MxK) * W(NxK)^T + b1 + b2, opt relu ----------
template<typename TC>
__global__ __launch_bounds__(256) void gemm_mfma(
  const bf16* __restrict__ A, const bf16* __restrict__ W,
  const float* __restrict__ b1, const float* __restrict__ b2,
  TC* __restrict__ Cv, int M, int N, int K, int relu)
{
  __shared__ bf16 As[128][40];
  __shared__ bf16 Bs[128][40];
  int tid = threadIdx.x;
  int wave = tid>>6, lane = tid&63, l15 = lane&15, quad = lane>>4;
  int m0 = blockIdx.y*128, n0 = blockIdx.x*128;
  int wm = (wave>>1)*64, wn = (wave&1)*64;
  int srow = tid>>1, scw = (tid&1)*16;
  const bf16* Ap = A + (size_t)(m0+srow)*K + scw;
  const bf16* Wp = W + (size_t)(n0+srow)*K + scw;
  floatx4 zero = {0.f,0.f,0.f,0.f};
  floatx4 acc[4][4];
  #pragma unroll
  for (int i=0;i<4;i++)
    #pragma unroll
    for (int j=0;j<4;j++) acc[i][j] = zero;

  for (int k0 = 0; k0 < K; k0 += 32) {
    float4 a0 = *(const float4*)Ap, a1 = *(const float4*)(Ap+8);
    float4 w0 = *(const float4*)Wp, w1 = *(const float4*)(Wp+8);
    Ap += 32; Wp += 32;
    __syncthreads();
    *(float4*)&As[srow][scw]   = a0; *(float4*)&As[srow][scw+8] = a1;
    *(float4*)&Bs[srow][scw]   = w0; *(float4*)&Bs[srow][scw+8] = w1;
    __syncthreads();
    short8 af[4], bfv[4];
    #pragma unroll
    for (int mi=0;mi<4;mi++) af[mi]  = *(const short8*)&As[wm+mi*16+l15][quad*8];
    #pragma unroll
    for (int ni=0;ni<4;ni++) bfv[ni] = *(const short8*)&Bs[wn+ni*16+l15][quad*8];
    #pragma unroll
    for (int mi=0;mi<4;mi++)
      #pragma unroll
      for (int ni=0;ni<4;ni++)
        acc[mi][ni] = __builtin_amdgcn_mfma_f32_16x16x32_bf16(af[mi], bfv[ni], acc[mi][ni], 0,0,0);
  }
  #pragma unroll
  for (int mi=0;mi<4;mi++){
    #pragma unroll
    for (int ni=0;ni<4;ni++){
      int n = n0 + wn + ni*16 + l15;
      float bb = (b1 ? b1[n] : 0.f) + (b2 ? b2[n] : 0.f);
      #pragma unroll
      for (int r=0;r<4;r++){
        int m = m0 + wm + mi*16 + quad*4 + r;
        float v = acc[mi][ni][r] + bb;
        if (relu) v = fmaxf(v, 0.f);
        storev(&Cv[(size_t)m*N + n], v);
      }
    }
  }
}

// ---------- naive GEMM for fc3 (N=48) ----------
__global__ __launch_bounds__(256) void gemm_nt_small(
  const bf16* __restrict__ A, const float* __restrict__ W,
  const float* __restrict__ b1, float* __restrict__ Cv, int M, int N, int K)
{
  __shared__ float As[8][128];
  __shared__ float Ws[8][128];
  int tid = threadIdx.x;
  int tx = tid & 15, ty = tid >> 4;
  int m0 = blockIdx.y * 128, n0 = blockIdx.x * 128;
  int sr = tid >> 1;
  int sk = (tid & 1) * 4;
  const bf16* Ap = A + (size_t)(m0 + sr) * K + sk;
  bool wok = (n0 + sr) < N;
  const float* Wp = W + (size_t)(wok ? (n0 + sr) : 0) * K + sk;
  float acc[8][8] = {};
  for (int k0 = 0; k0 < K; k0 += 8) {
    float av[4], wv[4];
    load4f(Ap, av);
    if (wok) { float4 t = *(const float4*)Wp; wv[0]=t.x; wv[1]=t.y; wv[2]=t.z; wv[3]=t.w; }
    else { wv[0]=wv[1]=wv[2]=wv[3]=0.f; }
    Ap += 8; Wp += 8;
    __syncthreads();
    As[sk+0][sr]=av[0]; As[sk+1][sr]=av[1]; As[sk+2][sr]=av[2]; As[sk+3][sr]=av[3];
    Ws[sk+0][sr]=wv[0]; Ws[sk+1][sr]=wv[1]; Ws[sk+2][sr]=wv[2]; Ws[sk+3][sr]=wv[3];
    __syncthreads();
    #pragma unroll
    for (int kk = 0; kk < 8; kk++) {
      float a[8], w[8];
      *(float4*)&a[0] = *(const float4*)&As[kk][ty*8];
      *(float4*)&a[4] = *(const float4*)&As[kk][ty*8+4];
      *(float4*)&w[0] = *(const float4*)&Ws[kk][tx*8];
      *(float4*)&w[4] = *(const float4*)&Ws[kk][tx*8+4];
      #pragma unroll
      for (int i=0;i<8;i++)
        #pragma unroll
        for (int j=0;j<8;j++) acc[i][j] += a[i]*w[j];
    }
  }
  #pragma unroll
  for (int i=0;i<8;i++){
    int m = m0 + ty*8 + i;
    #pragma unroll
    for (int j=0;j<8;j++){
      int n = n0 + tx*8 + j;
      if (n < N) Cv[(size_t)m*N + n] = acc[i][j] + b1[n];
    }
  }
}

// ---------- persistent BiLSTM layer: 64 blocks = dir(2) x jslice(32 of 16 units) ----------
// v12 = v10b + contention-free arrival/release. v10b's remaining modeled cost is the
// 32 same-word fetch_adds serialized at the MALL (~3-6K cy/step). Changes:
//  * arrival: tid0 plain system-scope STORE of t+1 into its OWN stamp word
//    (32 distinct words per dir, monotone, no reset, no RMW).
//  * release: all 64 lanes poll stamp[dir*32 + (lane&31)] (1 load/lane in the
//    poll's vmcnt scope) with __any(v <= t) - wave-autonomous.
// (The rare 20-45ms outlier passes previously blamed on store-stamps also appear
// on crf_k, which has no persistent sync - they are cold-replay artifacts.)
// Everything else byte-identical to v10b: block-major h, LDS-staged wide stores
// (128 threads x 2x8B line-contiguous system-scope), system-scope af loads,
// af-first/pgn-behind schedule, xout after stamp.
__global__ __launch_bounds__(256,1) void lstm_persist(
  const bf16* __restrict__ preF, const bf16* __restrict__ preB,
  const bf16* __restrict__ WF, const bf16* __restrict__ WB,   // Whh bf16 2048x512 row-major
  bf16* __restrict__ hbuf,          // BLOCK-MAJOR [2 pp][2 dir][32][64][16]
  bf16* __restrict__ xout,          // [64][256][1024]
  const float* __restrict__ bnscale, const float* __restrict__ bnshift,
  int* __restrict__ stamps)         // [2 dir][32 blocks], zeroed before launch
{
  __shared__ bf16 wlds[64][520];    // 64 gate-rows x 512 k, +8 pad
  __shared__ bf16 htmp[64][16];     // h staging: [b][unit-local]
  int blk = blockIdx.x;
  int dir = blk & 1;
  int js  = blk >> 1;               // 0..31
  int j0  = js * 16;
  const bf16* pre = dir ? preB : preF;
  const bf16* W   = dir ? WB : WF;
  int colOff = dir ? Hz : 0;
  int tid = threadIdx.x;
  int wave = tid >> 6, lane = tid & 63, l15 = lane & 15, quad = lane >> 4;
  int* st = stamps + dir*32;

  // --- load weight slice once: lds row n = g*16+idx <-> Whh row g*512 + j0 + idx ---
  for (int chunk = tid; chunk < 64*64; chunk += 256) {
    int n = chunk >> 6, col = (chunk & 63) * 8;
    int g = n >> 4, idx = n & 15;
    *(float4*)&wlds[n][col] = *(const float4*)(W + ((size_t)(g*512 + j0 + idx))*Hz + col);
  }
  __syncthreads();

  int bb = wave*16 + quad*4;        // batch base for this lane's accumulator rows
  int j  = j0 + l15;                // this lane's hidden unit
  float sc = bnscale ? bnscale[colOff + j] : 1.f;
  float sh = bnshift ? bnshift[colOff + j] : 0.f;
  int useBN = bnscale ? 1 : 0;
  float c[4] = {0.f,0.f,0.f,0.f};

  // prefetch pre-activations for step 0
  float pg[4][4];
  {
    int t0 = dir ? (Sz-1) : 0;
    #pragma unroll
    for (int r=0;r<4;r++){
      const bf16* pb = pre + ((size_t)(bb+r)*Sz + t0)*FH;
      #pragma unroll
      for (int g=0;g<4;g++) pg[g][r] = b2f(pb[g*512 + j]);
    }
  }

  for (int t = 0; t < Sz; t++) {
    int tcur = dir ? (Sz-1-t) : t;
    floatx4 zero = {0.f,0.f,0.f,0.f};
    floatx4 acc[4] = {zero, zero, zero, zero};

    // 1) h fragments from the MALL (system-scope atomic b64 loads), issued FIRST.
    //    Block-major: fragment (ks,quad) -> region js'=2*ks+(quad>>1), offset
    //    (quad&1)*8.
    short8 af[16];
    if (t > 0) {
      const bf16* hprev = hbuf + ((size_t)((t&1)*2 + dir))*Bz*Hz;
      #pragma unroll
      for (int ks=0;ks<16;ks++){
        int jsrc = 2*ks + (quad>>1);
        const u64* hp = (const u64*)(hprev + ((size_t)(jsrc*64 + wave*16 + l15)*16 + (quad&1)*8));
        union { u64 q[2]; short8 v; } uu;
        uu.q[0] = __hip_atomic_load(hp,     __ATOMIC_RELAXED, __HIP_MEMORY_SCOPE_SYSTEM);
        uu.q[1] = __hip_atomic_load(hp + 1, __ATOMIC_RELAXED, __HIP_MEMORY_SCOPE_SYSTEM);
        af[ks] = uu.v;
      }
    }

    // 2) prefetch NEXT step's pre-activations, issued BEHIND the h loads:
    //    MFMA waits only on af (partial vmcnt); these drain under MFMA+gates+barrier
    //    and are consumed next iteration. Normal cached loads.
    float pgn[4][4];
    if (t+1 < Sz) {
      int tnext = dir ? (Sz-2-t) : (t+1);
      #pragma unroll
      for (int r=0;r<4;r++){
        const bf16* pb = pre + ((size_t)(bb+r)*Sz + tnext)*FH;
        #pragma unroll
        for (int g=0;g<4;g++) pgn[g][r] = b2f(pb[g*512 + j]);
      }
    }

    // 3) MFMA (needs only af)
    if (t > 0) {
      #pragma unroll
      for (int g=0; g<4; g++)
        #pragma unroll
        for (int ks=0; ks<16; ks++){
          short8 bfv = *(const short8*)&wlds[g*16 + l15][ks*32 + quad*8];
          acc[g] = __builtin_amdgcn_mfma_f32_16x16x32_bf16(af[ks], bfv, acc[g], 0,0,0);
        }
    }

    // 4) gates (pg prefetched last iteration); h goes to LDS staging buffer
    float hval[4];
    #pragma unroll
    for (int r=0;r<4;r++){
      float gi = acc[0][r] + pg[0][r];
      float gf = acc[1][r] + pg[1][r];
      float gg = acc[2][r] + pg[2][r];
      float go = acc[3][r] + pg[3][r];
      float cv = fsig(gf)*c[r] + fsig(gi)*ftanh(gg);
      float h  = fsig(go)*ftanh(cv);
      c[r] = cv;
      hval[r] = h;
      htmp[bb+r][l15] = __float2bfloat16(h);
    }

    if (t < Sz-1) {
      // 5) coalesced h publish: 128 threads x two contiguous 8B MALL stores,
      //    explicit drain, rendezvous, then ONE plain store into our OWN stamp
      //    word (no RMW, no same-address contention).
      __syncthreads();                       // htmp complete
      if (tid < 128) {
        int b = tid >> 1, half = tid & 1;
        bf16* hnext = hbuf + ((size_t)(((t+1)&1)*2 + dir))*Bz*Hz;
        u64* dst = (u64*)(hnext + ((size_t)(js*64 + b)*16 + half*8));
        const u64* src = (const u64*)&htmp[b][half*8];
        u64 v0 = src[0], v1 = src[1];
        __hip_atomic_store(dst,     v0, __ATOMIC_RELAXED, __HIP_MEMORY_SCOPE_SYSTEM);
        __hip_atomic_store(dst + 1, v1, __ATOMIC_RELAXED, __HIP_MEMORY_SCOPE_SYSTEM);
      }
      asm volatile("s_waitcnt vmcnt(0) lgkmcnt(0)" ::: "memory");
      __syncthreads();                       // all stores drained before stamp
      if (tid == 0)
        __hip_atomic_store(&st[js], t+1, __ATOMIC_RELAXED, __HIP_MEMORY_SCOPE_SYSTEM);

      // 6) xout stores after the stamp: acks overlap the poll
      #pragma unroll
      for (int r=0;r<4;r++){
        float xv = useBN ? (hval[r]*sc + sh) : hval[r];
        xout[((size_t)(bb+r)*Sz + tcur)*OH + colOff + j] = __float2bfloat16(xv);
      }

      // 7) release: wave-autonomous poll of all 32 stamps (1 load/lane in the
      //    poll's vmcnt scope; lanes 32-63 mirror 0-31)
      int v;
      do {
        v = __hip_atomic_load(&st[lane & 31], __ATOMIC_RELAXED, __HIP_MEMORY_SCOPE_SYSTEM);
      } while (__any(v <= t));
      asm volatile("" ::: "memory");

      #pragma unroll
      for (int g=0;g<4;g++)
        #pragma unroll
        for (int r=0;r<4;r++) pg[g][r] = pgn[g][r];
    } else {
      #pragma unroll
      for (int r=0;r<4;r++){
        float xv = useBN ? (hval[r]*sc + sh) : hval[r];
        xout[((size_t)(bb+r)*Sz + tcur)*OH + colOff + j] = __float2bfloat16(xv);
      }
    }
  }
}

// ---------- CRF ----------
__global__ __launch_bounds__(64) void crf_k(const float* __restrict__ em, const int* __restrict__ tags,
  const float* __restrict__ start, const float* __restrict__ endv, const float* __restrict__ trans,
  float* __restrict__ result)
{
  __shared__ float tr[Tz*Tz];
  __shared__ float alpha[2][Tz];
  int b = blockIdx.x, tid = threadIdx.x;
  for (int i = tid; i < Tz*Tz; i += 64) tr[i] = trans[i];
  float np = 0.f;
  for (int t = tid; t < Sz; t += 64) {
    int tg = tags[b*Sz + t];
    np += em[((size_t)b*Sz + t)*Tz + tg];
    if (t+1 < Sz) np += trans[tg*Tz + tags[b*Sz + t + 1]];
  }
  #pragma unroll
  for (int off = 32; off; off >>= 1) np += __shfl_down(np, off);
  float num = 0.f;
  if (tid == 0) num = np + start[tags[b*Sz]] + endv[tags[b*Sz + Sz-1]];
  if (tid < Tz) alpha[0][tid] = start[tid] + em[((size_t)b*Sz)*Tz + tid];
  __syncthreads();
  int cur = 0;
  for (int t = 1; t < Sz; t++) {
    if (tid < Tz) {
      float m = -1e30f;
      for (int i = 0; i < Tz; i++) m = fmaxf(m, alpha[cur][i] + tr[i*Tz + tid]);
      float sum = 0.f;
      for (int i = 0; i < Tz; i++) sum += expf(alpha[cur][i] + tr[i*Tz + tid] - m);
      alpha[1-cur][tid] = m + logf(sum) + em[((size_t)b*Sz + t)*Tz + tid];
    }
    cur ^= 1;
    __syncthreads();
  }
  float a = (tid < Tz) ? alpha[cur][tid] + endv[tid] : -1e30f;
  float m = a;
  #pragma unroll
  for (int off = 32; off; off >>= 1) m = fmaxf(m, __shfl_down(m, off));
  m = __shfl(m, 0);
  float e = (tid < Tz) ? expf(a - m) : 0.f;
  #pragma unroll
  for (int off = 32; off; off >>= 1) e += __shfl_down(e, off);
  if (tid == 0) result[b] = num - (m + logf(e));
}

__global__ __launch_bounds__(64) void finalize_k(const float* __restrict__ result, float* __restrict__ outp)
{
  float v = result[threadIdx.x];
  #pragma unroll
  for (int off = 32; off; off >>= 1) v += __shfl_down(v, off);
  if (threadIdx.x == 0) outp[0] = -(v * (1.f/64.f));
}

extern "C" void kernel_launch(void* const* d_in, const int* in_sizes, int n_in,
                              void* d_out, int out_size, void* d_ws, size_t ws_size,
                              hipStream_t stream)
{
  (void)in_sizes; (void)n_in; (void)out_size; (void)ws_size;
  const float* inputs = (const float*)d_in[0];
  const int*   tags   = (const int*)d_in[1];
  const float* Wih[2][2] = {{(const float*)d_in[2],  (const float*)d_in[6]},
                            {(const float*)d_in[10], (const float*)d_in[14]}};
  const float* Whh[2][2] = {{(const float*)d_in[3],  (const float*)d_in[7]},
                            {(const float*)d_in[11], (const float*)d_in[15]}};
  const float* bih[2][2] = {{(const float*)d_in[4],  (const float*)d_in[8]},
                            {(const float*)d_in[12], (const float*)d_in[16]}};
  const float* bhh[2][2] = {{(const float*)d_in[5],  (const float*)d_in[9]},
                            {(const float*)d_in[13], (const float*)d_in[17]}};
  const float* bn_gamma = (const float*)d_in[18];
  const float* bn_beta  = (const float*)d_in[19];
  const float* bn_mean  = (const float*)d_in[20];
  const float* bn_var   = (const float*)d_in[21];
  const float* fc1_w = (const float*)d_in[22];
  const float* fc1_b = (const float*)d_in[23];
  const float* fc2_w = (const float*)d_in[24];
  const float* fc2_b = (const float*)d_in[25];
  const float* fc3_w = (const float*)d_in[26];
  const float* fc3_b = (const float*)d_in[27];
  const float* crf_start = (const float*)d_in[28];
  const float* crf_end   = (const float*)d_in[29];
  const float* crf_trans = (const float*)d_in[30];

  const size_t M = (size_t)Bz*Sz;   // 16384
  char* p = (char*)d_ws;
  auto alloc = [&](size_t bytes) { char* r = p; p += (bytes + 255) & ~(size_t)255; return r; };
  bf16*  preF  = (bf16*) alloc(M*FH*sizeof(bf16));            // 64 MB
  bf16*  preB  = (bf16*) alloc(M*FH*sizeof(bf16));            // 64 MB
  bf16*  xbuf  = (bf16*) alloc(M*OH*sizeof(bf16));            // 32 MB
  bf16*  inbf  = (bf16*) alloc(M*Dz*sizeof(bf16));            // 8 MB (em overlays later)
  bf16*  Wih0A = (bf16*) alloc((size_t)FH*Dz*sizeof(bf16));   // 1 MB
  bf16*  Wih0B = (bf16*) alloc((size_t)FH*Dz*sizeof(bf16));
  bf16*  Wih1A = (bf16*) alloc((size_t)FH*OH*sizeof(bf16));   // 4 MB
  bf16*  Wih1B = (bf16*) alloc((size_t)FH*OH*sizeof(bf16));
  bf16*  Whh0A = (bf16*) alloc((size_t)FH*Hz*sizeof(bf16));   // 2 MB
  bf16*  Whh0B = (bf16*) alloc((size_t)FH*Hz*sizeof(bf16));
  bf16*  Whh1A = (bf16*) alloc((size_t)FH*Hz*sizeof(bf16));
  bf16*  Whh1B = (bf16*) alloc((size_t)FH*Hz*sizeof(bf16));
  bf16*  fc1wb = (bf16*) alloc((size_t)Hz*OH*sizeof(bf16));   // 1 MB
  bf16*  fc2wb = (bf16*) alloc((size_t)256*Hz*sizeof(bf16));  // 0.25 MB
  bf16*  hbuf  = (bf16*) alloc(4*(size_t)Bz*Hz*sizeof(bf16)); // 256 KB (pp x dir, block-major)
  int*   stamps= (int*)  alloc(256*sizeof(int));              // 2 layers x (2 dir x 32)
  float* bnscale = (float*)alloc(OH*sizeof(float));
  float* bnshift = (float*)alloc(OH*sizeof(float));
  float* result  = (float*)alloc(Bz*sizeof(float));
  float* em   = (float*)inbf;                                 // overlay (3 MB <= 8 MB)
  bf16* fc1o = (bf16*)preF;                                   // overlays after recurrence
  bf16* fc2o = (bf16*)preB;

  dim3 tb(256);
  auto cast = [&](const float* src, bf16* dst, size_t n){
    castf2b<<<(n/4 + 255)/256, tb, 0, stream>>>(src, dst, (int)n);
  };

  // stamp words must be zero (ws is poisoned 0xAA before every run)
  hipMemsetAsync(stamps, 0, 256*sizeof(int), stream);
  // upfront casts (all independent of compute)
  cast(inputs, inbf, M*Dz);
  cast(Wih[0][0], Wih0A, (size_t)FH*Dz);
  cast(Wih[0][1], Wih0B, (size_t)FH*Dz);
  cast(Wih[1][0], Wih1A, (size_t)FH*OH);
  cast(Wih[1][1], Wih1B, (size_t)FH*OH);
  cast(Whh[0][0], Whh0A, (size_t)FH*Hz);
  cast(Whh[0][1], Whh0B, (size_t)FH*Hz);
  cast(Whh[1][0], Whh1A, (size_t)FH*Hz);
  cast(Whh[1][1], Whh1B, (size_t)FH*Hz);
  cast(fc1_w, fc1wb, (size_t)Hz*OH);
  cast(fc2_w, fc2wb, (size_t)256*Hz);
  bnprep_k<<<OH/256, tb, 0, stream>>>(bn_gamma, bn_beta, bn_mean, bn_var, bnscale, bnshift);

  // ---- layer 0 ----
  gemm_mfma<bf16><<<dim3(FH/128, M/128), tb, 0, stream>>>(inbf, Wih0A, bih[0][0], bhh[0][0], preF, M, FH, Dz, 0);
  gemm_mfma<bf16><<<dim3(FH/128, M/128), tb, 0, stream>>>(inbf, Wih0B, bih[0][1], bhh[0][1], preB, M, FH, Dz, 0);
  lstm_persist<<<64, tb, 0, stream>>>(preF, preB, Whh0A, Whh0B, hbuf, xbuf, nullptr, nullptr, stamps);
  // ---- layer 1 ----
  gemm_mfma<bf16><<<dim3(FH/128, M/128), tb, 0, stream>>>(xbuf, Wih1A, bih[1][0], bhh[1][0], preF, M, FH, OH, 0);
  gemm_mfma<bf16><<<dim3(FH/128, M/128), tb, 0, stream>>>(xbuf, Wih1B, bih[1][1], bhh[1][1], preB, M, FH, OH, 0);
  lstm_persist<<<64, tb, 0, stream>>>(preF, preB, Whh1A, Whh1B, hbuf, xbuf, bnscale, bnshift, stamps + 128);
  // ---- head ----
  gemm_mfma<bf16><<<dim3(Hz/128, M/128), tb, 0, stream>>>(xbuf, fc1wb, fc1_b, nullptr, fc1o, M, Hz, OH, 1);
  gemm_mfma<bf16><<<dim3(256/128, M/128), tb, 0, stream>>>(fc1o, fc2wb, fc2_b, nullptr, fc2o, M, 256, Hz, 1);
  gemm_nt_small<<<dim3(1, M/128), tb, 0, stream>>>(fc2o, fc3_w, fc3_b, em, M, Tz, 256);
  crf_k<<<Bz, 64, 0, stream>>>(em, tags, crf_start, crf_end, crf_trans, result);
  finalize_k<<<1, 64, 0, stream>>>(result, (float*)d_out);
}

// Round 14
// 3665.282 us; speedup vs baseline: 1.1294x; 1.0112x over previous
//
#include <hip/hip_runtime.h>
#include <hip/hip_bf16.h>
#include <math.h>

#define Bz 64
#define Sz 256
#define Dz 256
#define Hz 512
#define FH 2048   // 4H
#define OH 1024   // 2H
#define Tz 48
#define EPSV 1e-5f
#define LOG2E 1.44269504f

typedef __hip_bfloat16 bf16;
typedef __attribute__((ext_vector_type(8))) short short8;
typedef __attribute__((ext_vector_type(4))) float floatx4;
typedef unsigned long long u64;

__device__ __forceinline__ float b2f(bf16 v){ return __bfloat162float(v); }
// fast sigmoid/tanh on v_exp_f32 / v_rcp_f32
__device__ __forceinline__ float fsig(float x){
  float e = __builtin_amdgcn_exp2f(-x*LOG2E);
  return __builtin_amdgcn_rcpf(1.f + e);
}
__device__ __forceinline__ float ftanh(float x){
  float e = __builtin_amdgcn_exp2f(x*(2.f*LOG2E));
  return 1.f - 2.f*__builtin_amdgcn_rcpf(e + 1.f);
}

__device__ __forceinline__ void load4f(const bf16* p, float v[4]) {
  ushort4 t = *(const ushort4*)p;
  v[0] = __uint_as_float(((unsigned)t.x) << 16);
  v[1] = __uint_as_float(((unsigned)t.y) << 16);
  v[2] = __uint_as_float(((unsigned)t.z) << 16);
  v[3] = __uint_as_float(((unsigned)t.w) << 16);
}
__device__ __forceinline__ void storev(float* p, float v){ *p = v; }
__device__ __forceinline__ void storev(bf16* p, float v){ *p = __float2bfloat16(v); }

// ---------- fp32 -> bf16 cast ----------
__global__ __launch_bounds__(256) void castf2b(const float* __restrict__ in, bf16* __restrict__ out, int n)
{
  int i = (blockIdx.x*256 + threadIdx.x)*4;
  if (i >= n) return;
  float4 v = *(const float4*)(in + i);
  bf16 tmp[4];
  tmp[0] = __float2bfloat16(v.x); tmp[1] = __float2bfloat16(v.y);
  tmp[2] = __float2bfloat16(v.z); tmp[3] = __float2bfloat16(v.w);
  *(uint2*)(out + i) = *(const uint2*)tmp;
}

__global__ __launch_bounds__(256) void bnprep_k(const float* __restrict__ gamma, const float* __restrict__ beta,
  const float* __restrict__ mean, const float* __restrict__ var,
  float* __restrict__ scale, float* __restrict__ shift)
{
  int i = blockIdx.x*256 + threadIdx.x;
  if (i >= OH) return;
  float s = gamma[i]*rsqrtf(var[i]+EPSV);
  scale[i] = s; shift[i] = beta[i] - mean[i]*s;
}

// ---------- MFMA bf16 GEMM: C = A(MxK) * W(NxK)^T + b1 + b2, opt relu ----------
// v14: m97-style staging - global_load_lds width=16 direct global->LDS (no register
// round-trip, no VALU address pressure). LDS is LINEAR [128][32] (lane-linear
// contiguous destinations required by global_load_lds). Per K-step: 4 calls/thread
// (2 A halves, 2 B halves), vmcnt(0)+barrier, then unchanged ds_read b128 + 16 MFMA.
// Guide-measured: this staging step was 517->874 TF on the same 128x128 tile.
template<typename TC>
__global__ __launch_bounds__(256) void gemm_mfma(
  const bf16* __restrict__ A, const bf16* __restrict__ W,
  const float* __restrict__ b1, const float* __restrict__ b2,
  TC* __restrict__ Cv, int M, int N, int K, int relu)
{
  __shared__ bf16 As[128*32];
  __shared__ bf16 Bs[128*32];
  int tid = threadIdx.x;
  int wave = tid>>6, lane = tid&63, l15 = lane&15, quad = lane>>4;
  int m0 = blockIdx.y*128, n0 = blockIdx.x*128;
  int wm = (wave>>1)*64, wn = (wave&1)*64;
  int rr = lane>>2;              // 0..15 : row within a 16-row call group
  int cc = (lane&3)*8;           // 0,8,16,24 : col chunk (8 bf16 = 16B)
  floatx4 zero = {0.f,0.f,0.f,0.f};
  floatx4 acc[4][4];
  #pragma unroll
  for (int i=0;i<4;i++)
    #pragma unroll
    for (int j=0;j<4;j++) acc[i][j] = zero;

  for (int k0 = 0; k0 < K; k0 += 32) {
    __syncthreads();             // consumers done with LDS from previous iter
    #pragma unroll
    for (int h=0;h<2;h++){
      int r = (h*4 + wave)*16 + rr;              // 8 call-groups x 16 rows = 128
      const bf16* ga = A + (size_t)(m0+r)*K + k0 + cc;
      const bf16* gw = W + (size_t)(n0+r)*K + k0 + cc;
      bf16* la = As + r*32 + cc;                 // lane-linear: base + lane*16B
      bf16* lb = Bs + r*32 + cc;
      __builtin_amdgcn_global_load_lds(
        (const __attribute__((address_space(1))) unsigned int*)ga,
        (__attribute__((address_space(3))) unsigned int*)la, 16, 0, 0);
      __builtin_amdgcn_global_load_lds(
        (const __attribute__((address_space(1))) unsigned int*)gw,
        (__attribute__((address_space(3))) unsigned int*)lb, 16, 0, 0);
    }
    asm volatile("s_waitcnt vmcnt(0)" ::: "memory");
    __syncthreads();
    short8 af[4], bfv[4];
    #pragma unroll
    for (int mi=0;mi<4;mi++) af[mi]  = *(const short8*)(As + (wm+mi*16+l15)*32 + quad*8);
    #pragma unroll
    for (int ni=0;ni<4;ni++) bfv[ni] = *(const short8*)(Bs + (wn+ni*16+l15)*32 + quad*8);
    #pragma unroll
    for (int mi=0;mi<4;mi++)
      #pragma unroll
      for (int ni=0;ni<4;ni++)
        acc[mi][ni] = __builtin_amdgcn_mfma_f32_16x16x32_bf16(af[mi], bfv[ni], acc[mi][ni], 0,0,0);
  }
  #pragma unroll
  for (int mi=0;mi<4;mi++){
    #pragma unroll
    for (int ni=0;ni<4;ni++){
      int n = n0 + wn + ni*16 + l15;
      float bb = (b1 ? b1[n] : 0.f) + (b2 ? b2[n] : 0.f);
      #pragma unroll
      for (int r=0;r<4;r++){
        int m = m0 + wm + mi*16 + quad*4 + r;
        float v = acc[mi][ni][r] + bb;
        if (relu) v = fmaxf(v, 0.f);
        storev(&Cv[(size_t)m*N + n], v);
      }
    }
  }
}

// ---------- naive GEMM for fc3 (N=48) ----------
__global__ __launch_bounds__(256) void gemm_nt_small(
  const bf16* __restrict__ A, const float* __restrict__ W,
  const float* __restrict__ b1, float* __restrict__ Cv, int M, int N, int K)
{
  __shared__ float As[8][128];
  __shared__ float Ws[8][128];
  int tid = threadIdx.x;
  int tx = tid & 15, ty = tid >> 4;
  int m0 = blockIdx.y * 128, n0 = blockIdx.x * 128;
  int sr = tid >> 1;
  int sk = (tid & 1) * 4;
  const bf16* Ap = A + (size_t)(m0 + sr) * K + sk;
  bool wok = (n0 + sr) < N;
  const float* Wp = W + (size_t)(wok ? (n0 + sr) : 0) * K + sk;
  float acc[8][8] = {};
  for (int k0 = 0; k0 < K; k0 += 8) {
    float av[4], wv[4];
    load4f(Ap, av);
    if (wok) { float4 t = *(const float4*)Wp; wv[0]=t.x; wv[1]=t.y; wv[2]=t.z; wv[3]=t.w; }
    else { wv[0]=wv[1]=wv[2]=wv[3]=0.f; }
    Ap += 8; Wp += 8;
    __syncthreads();
    As[sk+0][sr]=av[0]; As[sk+1][sr]=av[1]; As[sk+2][sr]=av[2]; As[sk+3][sr]=av[3];
    Ws[sk+0][sr]=wv[0]; Ws[sk+1][sr]=wv[1]; Ws[sk+2][sr]=wv[2]; Ws[sk+3][sr]=wv[3];
    __syncthreads();
    #pragma unroll
    for (int kk = 0; kk < 8; kk++) {
      float a[8], w[8];
      *(float4*)&a[0] = *(const float4*)&As[kk][ty*8];
      *(float4*)&a[4] = *(const float4*)&As[kk][ty*8+4];
      *(float4*)&w[0] = *(const float4*)&Ws[kk][tx*8];
      *(float4*)&w[4] = *(const float4*)&Ws[kk][tx*8+4];
      #pragma unroll
      for (int i=0;i<8;i++)
        #pragma unroll
        for (int j=0;j<8;j++) acc[i][j] += a[i]*w[j];
    }
  }
  #pragma unroll
  for (int i=0;i<8;i++){
    int m = m0 + ty*8 + i;
    #pragma unroll
    for (int j=0;j<8;j++){
      int n = n0 + tx*8 + j;
      if (n < N) Cv[(size_t)m*N + n] = acc[i][j] + b1[n];
    }
  }
}

// ---------- persistent BiLSTM layer: 64 blocks = dir(2) x jslice(32 of 16 units) ----------
// v12 lstm (verified, 1311us): block-major h, LDS-staged wide system-scope stores,
// plain store-stamp arrival, wave-autonomous stamp poll, af-first/pgn-behind.
__global__ __launch_bounds__(256,1) void lstm_persist(
  const bf16* __restrict__ preF, const bf16* __restrict__ preB,
  const bf16* __restrict__ WF, const bf16* __restrict__ WB,   // Whh bf16 2048x512 row-major
  bf16* __restrict__ hbuf,          // BLOCK-MAJOR [2 pp][2 dir][32][64][16]
  bf16* __restrict__ xout,          // [64][256][1024]
  const float* __restrict__ bnscale, const float* __restrict__ bnshift,
  int* __restrict__ stamps)         // [2 dir][32 blocks], zeroed before launch
{
  __shared__ bf16 wlds[64][520];    // 64 gate-rows x 512 k, +8 pad
  __shared__ bf16 htmp[64][16];     // h staging: [b][unit-local]
  int blk = blockIdx.x;
  int dir = blk & 1;
  int js  = blk >> 1;               // 0..31
  int j0  = js * 16;
  const bf16* pre = dir ? preB : preF;
  const bf16* W   = dir ? WB : WF;
  int colOff = dir ? Hz : 0;
  int tid = threadIdx.x;
  int wave = tid >> 6, lane = tid & 63, l15 = lane & 15, quad = lane >> 4;
  int* st = stamps + dir*32;

  // --- load weight slice once: lds row n = g*16+idx <-> Whh row g*512 + j0 + idx ---
  for (int chunk = tid; chunk < 64*64; chunk += 256) {
    int n = chunk >> 6, col = (chunk & 63) * 8;
    int g = n >> 4, idx = n & 15;
    *(float4*)&wlds[n][col] = *(const float4*)(W + ((size_t)(g*512 + j0 + idx))*Hz + col);
  }
  __syncthreads();

  int bb = wave*16 + quad*4;        // batch base for this lane's accumulator rows
  int j  = j0 + l15;                // this lane's hidden unit
  float sc = bnscale ? bnscale[colOff + j] : 1.f;
  float sh = bnshift ? bnshift[colOff + j] : 0.f;
  int useBN = bnscale ? 1 : 0;
  float c[4] = {0.f,0.f,0.f,0.f};

  // prefetch pre-activations for step 0
  float pg[4][4];
  {
    int t0 = dir ? (Sz-1) : 0;
    #pragma unroll
    for (int r=0;r<4;r++){
      const bf16* pb = pre + ((size_t)(bb+r)*Sz + t0)*FH;
      #pragma unroll
      for (int g=0;g<4;g++) pg[g][r] = b2f(pb[g*512 + j]);
    }
  }

  for (int t = 0; t < Sz; t++) {
    int tcur = dir ? (Sz-1-t) : t;
    floatx4 zero = {0.f,0.f,0.f,0.f};
    floatx4 acc[4] = {zero, zero, zero, zero};

    // 1) h fragments from the MALL (system-scope atomic b64 loads), issued FIRST.
    //    Block-major: fragment (ks,quad) -> region js'=2*ks+(quad>>1), offset
    //    (quad&1)*8.
    short8 af[16];
    if (t > 0) {
      const bf16* hprev = hbuf + ((size_t)((t&1)*2 + dir))*Bz*Hz;
      #pragma unroll
      for (int ks=0;ks<16;ks++){
        int jsrc = 2*ks + (quad>>1);
        const u64* hp = (const u64*)(hprev + ((size_t)(jsrc*64 + wave*16 + l15)*16 + (quad&1)*8));
        union { u64 q[2]; short8 v; } uu;
        uu.q[0] = __hip_atomic_load(hp,     __ATOMIC_RELAXED, __HIP_MEMORY_SCOPE_SYSTEM);
        uu.q[1] = __hip_atomic_load(hp + 1, __ATOMIC_RELAXED, __HIP_MEMORY_SCOPE_SYSTEM);
        af[ks] = uu.v;
      }
    }

    // 2) prefetch NEXT step's pre-activations, issued BEHIND the h loads:
    //    MFMA waits only on af (partial vmcnt); these drain under MFMA+gates+barrier
    //    and are consumed next iteration. Normal cached loads.
    float pgn[4][4];
    if (t+1 < Sz) {
      int tnext = dir ? (Sz-2-t) : (t+1);
      #pragma unroll
      for (int r=0;r<4;r++){
        const bf16* pb = pre + ((size_t)(bb+r)*Sz + tnext)*FH;
        #pragma unroll
        for (int g=0;g<4;g++) pgn[g][r] = b2f(pb[g*512 + j]);
      }
    }

    // 3) MFMA (needs only af)
    if (t > 0) {
      #pragma unroll
      for (int g=0; g<4; g++)
        #pragma unroll
        for (int ks=0; ks<16; ks++){
          short8 bfv = *(const short8*)&wlds[g*16 + l15][ks*32 + quad*8];
          acc[g] = __builtin_amdgcn_mfma_f32_16x16x32_bf16(af[ks], bfv, acc[g], 0,0,0);
        }
    }

    // 4) gates (pg prefetched last iteration); h goes to LDS staging buffer
    float hval[4];
    #pragma unroll
    for (int r=0;r<4;r++){
      float gi = acc[0][r] + pg[0][r];
      float gf = acc[1][r] + pg[1][r];
      float gg = acc[2][r] + pg[2][r];
      float go = acc[3][r] + pg[3][r];
      float cv = fsig(gf)*c[r] + fsig(gi)*ftanh(gg);
      float h  = fsig(go)*ftanh(cv);
      c[r] = cv;
      hval[r] = h;
      htmp[bb+r][l15] = __float2bfloat16(h);
    }

    if (t < Sz-1) {
      // 5) coalesced h publish: 128 threads x two contiguous 8B MALL stores,
      //    explicit drain, rendezvous, then ONE plain store into our OWN stamp
      //    word (no RMW, no same-address contention).
      __syncthreads();                       // htmp complete
      if (tid < 128) {
        int b = tid >> 1, half = tid & 1;
        bf16* hnext = hbuf + ((size_t)(((t+1)&1)*2 + dir))*Bz*Hz;
        u64* dst = (u64*)(hnext + ((size_t)(js*64 + b)*16 + half*8));
        const u64* src = (const u64*)&htmp[b][half*8];
        u64 v0 = src[0], v1 = src[1];
        __hip_atomic_store(dst,     v0, __ATOMIC_RELAXED, __HIP_MEMORY_SCOPE_SYSTEM);
        __hip_atomic_store(dst + 1, v1, __ATOMIC_RELAXED, __HIP_MEMORY_SCOPE_SYSTEM);
      }
      asm volatile("s_waitcnt vmcnt(0) lgkmcnt(0)" ::: "memory");
      __syncthreads();                       // all stores drained before stamp
      if (tid == 0)
        __hip_atomic_store(&st[js], t+1, __ATOMIC_RELAXED, __HIP_MEMORY_SCOPE_SYSTEM);

      // 6) xout stores after the stamp: acks overlap the poll
      #pragma unroll
      for (int r=0;r<4;r++){
        float xv = useBN ? (hval[r]*sc + sh) : hval[r];
        xout[((size_t)(bb+r)*Sz + tcur)*OH + colOff + j] = __float2bfloat16(xv);
      }

      // 7) release: wave-autonomous poll of all 32 stamps (1 load/lane in the
      //    poll's vmcnt scope; lanes 32-63 mirror 0-31)
      int v;
      do {
        v = __hip_atomic_load(&st[lane & 31], __ATOMIC_RELAXED, __HIP_MEMORY_SCOPE_SYSTEM);
      } while (__any(v <= t));
      asm volatile("" ::: "memory");

      #pragma unroll
      for (int g=0;g<4;g++)
        #pragma unroll
        for (int r=0;r<4;r++) pg[g][r] = pgn[g][r];
    } else {
      #pragma unroll
      for (int r=0;r<4;r++){
        float xv = useBN ? (hval[r]*sc + sh) : hval[r];
        xout[((size_t)(bb+r)*Sz + tcur)*OH + colOff + j] = __float2bfloat16(xv);
      }
    }
  }
}

// ---------- CRF ----------
__global__ __launch_bounds__(64) void crf_k(const float* __restrict__ em, const int* __restrict__ tags,
  const float* __restrict__ start, const float* __restrict__ endv, const float* __restrict__ trans,
  float* __restrict__ result)
{
  __shared__ float tr[Tz*Tz];
  __shared__ float alpha[2][Tz];
  int b = blockIdx.x, tid = threadIdx.x;
  for (int i = tid; i < Tz*Tz; i += 64) tr[i] = trans[i];
  float np = 0.f;
  for (int t = tid; t < Sz; t += 64) {
    int tg = tags[b*Sz + t];
    np += em[((size_t)b*Sz + t)*Tz + tg];
    if (t+1 < Sz) np += trans[tg*Tz + tags[b*Sz + t + 1]];
  }
  #pragma unroll
  for (int off = 32; off; off >>= 1) np += __shfl_down(np, off);
  float num = 0.f;
  if (tid == 0) num = np + start[tags[b*Sz]] + endv[tags[b*Sz + Sz-1]];
  if (tid < Tz) alpha[0][tid] = start[tid] + em[((size_t)b*Sz)*Tz + tid];
  __syncthreads();
  int cur = 0;
  for (int t = 1; t < Sz; t++) {
    if (tid < Tz) {
      float m = -1e30f;
      for (int i = 0; i < Tz; i++) m = fmaxf(m, alpha[cur][i] + tr[i*Tz + tid]);
      float sum = 0.f;
      for (int i = 0; i < Tz; i++) sum += expf(alpha[cur][i] + tr[i*Tz + tid] - m);
      alpha[1-cur][tid] = m + logf(sum) + em[((size_t)b*Sz + t)*Tz + tid];
    }
    cur ^= 1;
    __syncthreads();
  }
  float a = (tid < Tz) ? alpha[cur][tid] + endv[tid] : -1e30f;
  float m = a;
  #pragma unroll
  for (int off = 32; off; off >>= 1) m = fmaxf(m, __shfl_down(m, off));
  m = __shfl(m, 0);
  float e = (tid < Tz) ? expf(a - m) : 0.f;
  #pragma unroll
  for (int off = 32; off; off >>= 1) e += __shfl_down(e, off);
  if (tid == 0) result[b] = num - (m + logf(e));
}

__global__ __launch_bounds__(64) void finalize_k(const float* __restrict__ result, float* __restrict__ outp)
{
  float v = result[threadIdx.x];
  #pragma unroll
  for (int off = 32; off; off >>= 1) v += __shfl_down(v, off);
  if (threadIdx.x == 0) outp[0] = -(v * (1.f/64.f));
}

extern "C" void kernel_launch(void* const* d_in, const int* in_sizes, int n_in,
                              void* d_out, int out_size, void* d_ws, size_t ws_size,
                              hipStream_t stream)
{
  (void)in_sizes; (void)n_in; (void)out_size; (void)ws_size;
  const float* inputs = (const float*)d_in[0];
  const int*   tags   = (const int*)d_in[1];
  const float* Wih[2][2] = {{(const float*)d_in[2],  (const float*)d_in[6]},
                            {(const float*)d_in[10], (const float*)d_in[14]}};
  const float* Whh[2][2] = {{(const float*)d_in[3],  (const float*)d_in[7]},
                            {(const float*)d_in[11], (const float*)d_in[15]}};
  const float* bih[2][2] = {{(const float*)d_in[4],  (const float*)d_in[8]},
                            {(const float*)d_in[12], (const float*)d_in[16]}};
  const float* bhh[2][2] = {{(const float*)d_in[5],  (const float*)d_in[9]},
                            {(const float*)d_in[13], (const float*)d_in[17]}};
  const float* bn_gamma = (const float*)d_in[18];
  const float* bn_beta  = (const float*)d_in[19];
  const float* bn_mean  = (const float*)d_in[20];
  const float* bn_var   = (const float*)d_in[21];
  const float* fc1_w = (const float*)d_in[22];
  const float* fc1_b = (const float*)d_in[23];
  const float* fc2_w = (const float*)d_in[24];
  const float* fc2_b = (const float*)d_in[25];
  const float* fc3_w = (const float*)d_in[26];
  const float* fc3_b = (const float*)d_in[27];
  const float* crf_start = (const float*)d_in[28];
  const float* crf_end   = (const float*)d_in[29];
  const float* crf_trans = (const float*)d_in[30];

  const size_t M = (size_t)Bz*Sz;   // 16384
  char* p = (char*)d_ws;
  auto alloc = [&](size_t bytes) { char* r = p; p += (bytes + 255) & ~(size_t)255; return r; };
  bf16*  preF  = (bf16*) alloc(M*FH*sizeof(bf16));            // 64 MB
  bf16*  preB  = (bf16*) alloc(M*FH*sizeof(bf16));            // 64 MB
  bf16*  xbuf  = (bf16*) alloc(M*OH*sizeof(bf16));            // 32 MB
  bf16*  inbf  = (bf16*) alloc(M*Dz*sizeof(bf16));            // 8 MB (em overlays later)
  bf16*  Wih0A = (bf16*) alloc((size_t)FH*Dz*sizeof(bf16));   // 1 MB
  bf16*  Wih0B = (bf16*) alloc((size_t)FH*Dz*sizeof(bf16));
  bf16*  Wih1A = (bf16*) alloc((size_t)FH*OH*sizeof(bf16));   // 4 MB
  bf16*  Wih1B = (bf16*) alloc((size_t)FH*OH*sizeof(bf16));
  bf16*  Whh0A = (bf16*) alloc((size_t)FH*Hz*sizeof(bf16));   // 2 MB
  bf16*  Whh0B = (bf16*) alloc((size_t)FH*Hz*sizeof(bf16));
  bf16*  Whh1A = (bf16*) alloc((size_t)FH*Hz*sizeof(bf16));
  bf16*  Whh1B = (bf16*) alloc((size_t)FH*Hz*sizeof(bf16));
  bf16*  fc1wb = (bf16*) alloc((size_t)Hz*OH*sizeof(bf16));   // 1 MB
  bf16*  fc2wb = (bf16*) alloc((size_t)256*Hz*sizeof(bf16));  // 0.25 MB
  bf16*  hbuf  = (bf16*) alloc(4*(size_t)Bz*Hz*sizeof(bf16)); // 256 KB (pp x dir, block-major)
  int*   stamps= (int*)  alloc(256*sizeof(int));              // 2 layers x (2 dir x 32)
  float* bnscale = (float*)alloc(OH*sizeof(float));
  float* bnshift = (float*)alloc(OH*sizeof(float));
  float* result  = (float*)alloc(Bz*sizeof(float));
  float* em   = (float*)inbf;                                 // overlay (3 MB <= 8 MB)
  bf16* fc1o = (bf16*)preF;                                   // overlays after recurrence
  bf16* fc2o = (bf16*)preB;

  dim3 tb(256);
  auto cast = [&](const float* src, bf16* dst, size_t n){
    castf2b<<<(n/4 + 255)/256, tb, 0, stream>>>(src, dst, (int)n);
  };

  // stamp words must be zero (ws is poisoned 0xAA before every run)
  hipMemsetAsync(stamps, 0, 256*sizeof(int), stream);
  // upfront casts (all independent of compute)
  cast(inputs, inbf, M*Dz);
  cast(Wih[0][0], Wih0A, (size_t)FH*Dz);
  cast(Wih[0][1], Wih0B, (size_t)FH*Dz);
  cast(Wih[1][0], Wih1A, (size_t)FH*OH);
  cast(Wih[1][1], Wih1B, (size_t)FH*OH);
  cast(Whh[0][0], Whh0A, (size_t)FH*Hz);
  cast(Whh[0][1], Whh0B, (size_t)FH*Hz);
  cast(Whh[1][0], Whh1A, (size_t)FH*Hz);
  cast(Whh[1][1], Whh1B, (size_t)FH*Hz);
  cast(fc1_w, fc1wb, (size_t)Hz*OH);
  cast(fc2_w, fc2wb, (size_t)256*Hz);
  bnprep_k<<<OH/256, tb, 0, stream>>>(bn_gamma, bn_beta, bn_mean, bn_var, bnscale, bnshift);

  // ---- layer 0 ----
  gemm_mfma<bf16><<<dim3(FH/128, M/128), tb, 0, stream>>>(inbf, Wih0A, bih[0][0], bhh[0][0], preF, M, FH, Dz, 0);
  gemm_mfma<bf16><<<dim3(FH/128, M/128), tb, 0, stream>>>(inbf, Wih0B, bih[0][1], bhh[0][1], preB, M, FH, Dz, 0);
  lstm_persist<<<64, tb, 0, stream>>>(preF, preB, Whh0A, Whh0B, hbuf, xbuf, nullptr, nullptr, stamps);
  // ---- layer 1 ----
  gemm_mfma<bf16><<<dim3(FH/128, M/128), tb, 0, stream>>>(xbuf, Wih1A, bih[1][0], bhh[1][0], preF, M, FH, OH, 0);
  gemm_mfma<bf16><<<dim3(FH/128, M/128), tb, 0, stream>>>(xbuf, Wih1B, bih[1][1], bhh[1][1], preB, M, FH, OH, 0);
  lstm_persist<<<64, tb, 0, stream>>>(preF, preB, Whh1A, Whh1B, hbuf, xbuf, bnscale, bnshift, stamps + 128);
  // ---- head ----
  gemm_mfma<bf16><<<dim3(Hz/128, M/128), tb, 0, stream>>>(xbuf, fc1wb, fc1_b, nullptr, fc1o, M, Hz, OH, 1);
  gemm_mfma<bf16><<<dim3(256/128, M/128), tb, 0, stream>>>(fc1o, fc2wb, fc2_b, nullptr, fc2o, M, 256, Hz, 1);
  gemm_nt_small<<<dim3(1, M/128), tb, 0, stream>>>(fc2o, fc3_w, fc3_b, em, M, Tz, 256);
  crf_k<<<Bz, 64, 0, stream>>>(em, tags, crf_start, crf_end, crf_trans, result);
  finalize_k<<<1, 64, 0, stream>>>(result, (float*)d_out);
}